// Round 1
// baseline (1344.916 us; speedup 1.0000x reference)
//
#include <hip/hip_runtime.h>
#include <math.h>

#define DEPTH 18
#define NINT ((1 << (DEPTH - 1)) - 1)   // internal nodes (h/c stored)
#define NVOCAB 50000

typedef unsigned short bf16raw;
typedef __bf16 bf16x8 __attribute__((ext_vector_type(8)));
typedef float f32x4 __attribute__((ext_vector_type(4)));
typedef short short8 __attribute__((ext_vector_type(8)));

__device__ __forceinline__ float sigm(float x) { return 1.0f / (1.0f + __expf(-x)); }

__device__ __forceinline__ float bf2f(bf16raw u) {
    union { unsigned int i; float f; } v;
    v.i = ((unsigned int)u) << 16;
    return v.f;
}
__device__ __forceinline__ bf16raw f2bf(float f) {
    union { float f; unsigned int i; } v;
    v.f = f;
    unsigned int r = v.i + 0x7FFFu + ((v.i >> 16) & 1u);  // RNE
    return (bf16raw)(r >> 16);
}

// ---------------------------------------------------------------------------
__global__ __launch_bounds__(256) void k_prep_embeds(const float* __restrict__ src,
                                                     bf16raw* __restrict__ dst, int n4)
{
    int i = blockIdx.x * blockDim.x + threadIdx.x;
    if (i < n4) {
        float4 v = ((const float4*)src)[i];
        ushort4 o;
        o.x = f2bf(v.x); o.y = f2bf(v.y); o.z = f2bf(v.z); o.w = f2bf(v.w);
        ((ushort4*)dst)[i] = o;
    }
}

// ---------------------------------------------------------------------------
// BcatT[col 0..639][k 0..383] bf16.  Gate order: 0=i, 1=u, 2=o, 3=f1, 4=f2
// ---------------------------------------------------------------------------
__global__ __launch_bounds__(128) void k_prep_bcat(
    const float* __restrict__ Wix, const float* __restrict__ bix,
    const float* __restrict__ Wih, const float* __restrict__ bih,
    const float* __restrict__ Wfx, const float* __restrict__ bfx,
    const float* __restrict__ Wfh, const float* __restrict__ bfh,
    const float* __restrict__ Wox, const float* __restrict__ box_,
    const float* __restrict__ Woh, const float* __restrict__ boh,
    const float* __restrict__ Wux, const float* __restrict__ bux,
    const float* __restrict__ Wuh, const float* __restrict__ buh,
    bf16raw* __restrict__ BcatT, float* __restrict__ bias_cat)
{
    const int j = blockIdx.x;        // 0..639
    const int grp = j >> 7, jj = j & 127;
    const float *Wx, *Wh, *bx, *bh;
    switch (grp) {
        case 0: Wx = Wix; Wh = Wih; bx = bix;  bh = bih; break;
        case 1: Wx = Wux; Wh = Wuh; bx = bux;  bh = buh; break;
        case 2: Wx = Wox; Wh = Woh; bx = box_; bh = boh; break;
        default: Wx = Wfx; Wh = Wfh; bx = bfx; bh = bfh; break;
    }
    for (int k = threadIdx.x; k < 384; k += blockDim.x) {
        float v;
        if (k < 128) {
            v = Wx[jj * 128 + k];
        } else if (k < 256) {
            v = (grp == 4) ? 0.f : Wh[jj * 128 + (k - 128)];
        } else {
            v = (grp == 3) ? 0.f : Wh[jj * 128 + (k - 256)];
        }
        BcatT[(long)j * 384 + k] = f2bf(v);
    }
    if (threadIdx.x == 0) bias_cat[j] = bx[jj] + bh[jj];
}

// ---------------------------------------------------------------------------
// k_leafpre: per-vocab leaf tables. hc_leaf[v][0..127]=h, [128..255]=c;
// lossv6[v][0..4]=logits, [5]=lse.
// Restructured vs previous version to kill VGPR spills: compute c first
// (i -> u), flush c, keep tanh(c) in the same registers, then o -> h.
// Only one 64-reg state array is live at any time alongside acc.
// ---------------------------------------------------------------------------
__global__ __launch_bounds__(256, 2) void k_leafpre(
    const bf16raw* __restrict__ embeds_bf,
    const bf16raw* __restrict__ BcatT, const float* __restrict__ bias_cat,
    const float* __restrict__ Wout, const float* __restrict__ bout,
    bf16raw* __restrict__ hc_leaf, float* __restrict__ lossv6, int vbase, int nv)
{
    vbase += blockIdx.x * 128;
    nv -= vbase;
    if (nv > 128) nv = 128;
    if (nv <= 0) return;

    __shared__ __align__(16) bf16raw sA[128 * 40];
    __shared__ __align__(16) bf16raw sB[128 * 40];
    __shared__ __align__(16) bf16raw sT[128 * 136];
    __shared__ float sWout[5 * 128];

    const int t = threadIdx.x;
    for (int i = t; i < 640; i += 256) sWout[i] = Wout[i];

    const int srow = t >> 1;
    const int shalf = (t & 1) * 16;
    const int arow = (srow < nv) ? srow : 0;
    const bf16raw* ax = embeds_bf + (long)(vbase + arow) * 128;

    const int lane = t & 63;
    const int w = t >> 6;
    const int wrow = (w >> 1) * 64;
    const int wcol = (w & 1) * 64;
    const int lrow = lane & 15;
    const int lquad = lane >> 4;
    const int lkoff = lquad * 8;

    float tval[4][4][4];
    f32x4 acc[4][4];

    auto rungemm = [&](int cb) {
#pragma unroll
        for (int i = 0; i < 4; i++)
#pragma unroll
            for (int j = 0; j < 4; j++) acc[i][j] = (f32x4){0.f, 0.f, 0.f, 0.f};
        const bf16raw* bsrc = BcatT + ((long)(cb * 128 + srow)) * 384;
        for (int kt = 0; kt < 128; kt += 32) {
            short8 av0 = *(const short8*)(ax + kt + shalf);
            short8 av1 = *(const short8*)(ax + kt + shalf + 8);
            short8 bv0 = *(const short8*)(bsrc + kt + shalf);
            short8 bv1 = *(const short8*)(bsrc + kt + shalf + 8);
            __syncthreads();
            *(short8*)&sA[srow * 40 + shalf] = av0;
            *(short8*)&sA[srow * 40 + shalf + 8] = av1;
            *(short8*)&sB[srow * 40 + shalf] = bv0;
            *(short8*)&sB[srow * 40 + shalf + 8] = bv1;
            __syncthreads();
            bf16x8 af[4], bfr[4];
#pragma unroll
            for (int i = 0; i < 4; i++) {
                af[i]  = *(const bf16x8*)&sA[(wrow + i * 16 + lrow) * 40 + lkoff];
                bfr[i] = *(const bf16x8*)&sB[(wcol + i * 16 + lrow) * 40 + lkoff];
            }
#pragma unroll
            for (int i = 0; i < 4; i++)
#pragma unroll
                for (int j = 0; j < 4; j++)
                    acc[i][j] = __builtin_amdgcn_mfma_f32_16x16x32_bf16(af[i], bfr[j], acc[i][j], 0, 0, 0);
        }
    };

    // ---- i gate ----
    rungemm(0);
#pragma unroll
    for (int i = 0; i < 4; i++)
#pragma unroll
        for (int jj = 0; jj < 4; jj++) {
            const float b = bias_cat[wcol + jj * 16 + lrow];
#pragma unroll
            for (int r = 0; r < 4; r++) tval[i][jj][r] = sigm(acc[i][jj][r] + b);
        }
    // ---- u gate: tval = c = i*u ----
    rungemm(1);
#pragma unroll
    for (int i = 0; i < 4; i++)
#pragma unroll
        for (int jj = 0; jj < 4; jj++) {
            const float b = bias_cat[128 + wcol + jj * 16 + lrow];
#pragma unroll
            for (int r = 0; r < 4; r++) tval[i][jj][r] *= tanhf(acc[i][jj][r] + b);
        }
    // write c tile, then keep tanh(c) in regs
#pragma unroll
    for (int i = 0; i < 4; i++)
#pragma unroll
        for (int jj = 0; jj < 4; jj++)
#pragma unroll
            for (int r = 0; r < 4; r++) {
                const int m = wrow + i * 16 + lquad * 4 + r;
                const int j = wcol + jj * 16 + lrow;
                sT[m * 136 + j] = f2bf(tval[i][jj][r]);
            }
#pragma unroll
    for (int i = 0; i < 4; i++)
#pragma unroll
        for (int jj = 0; jj < 4; jj++)
#pragma unroll
            for (int r = 0; r < 4; r++) tval[i][jj][r] = tanhf(tval[i][jj][r]);
    __syncthreads();
    // flush c to hc_leaf[.., 128..255]
#pragma unroll
    for (int s = 0; s < 8; ++s) {
        int ci = t + 256 * s;
        int row = ci >> 4, c8 = (ci & 15) * 8;
        if (row < nv)
            *(short8*)(hc_leaf + (long)(vbase + row) * 256 + 128 + c8) = *(const short8*)&sT[row * 136 + c8];
    }
    // ---- o gate: h = sigm(o) * tanh(c) ----
    rungemm(2);
    __syncthreads();
#pragma unroll
    for (int i = 0; i < 4; i++)
#pragma unroll
        for (int jj = 0; jj < 4; jj++) {
            const float b = bias_cat[256 + wcol + jj * 16 + lrow];
#pragma unroll
            for (int r = 0; r < 4; r++) {
                const int m = wrow + i * 16 + lquad * 4 + r;
                const int j = wcol + jj * 16 + lrow;
                sT[m * 136 + j] = f2bf(sigm(acc[i][jj][r] + b) * tval[i][jj][r]);
            }
        }
    __syncthreads();
    // flush h to hc_leaf[.., 0..127]
#pragma unroll
    for (int s = 0; s < 8; ++s) {
        int ci = t + 256 * s;
        int row = ci >> 4, c8 = (ci & 15) * 8;
        if (row < nv)
            *(short8*)(hc_leaf + (long)(vbase + row) * 256 + c8) = *(const short8*)&sT[row * 136 + c8];
    }
    // logits + lse per vocab row
    {
        const int row = t >> 1, half = t & 1;
        float p[5] = {0.f, 0.f, 0.f, 0.f, 0.f};
        for (int k = 0; k < 64; ++k) {
            float hv = bf2f(sT[row * 136 + half * 64 + k]);
#pragma unroll
            for (int l = 0; l < 5; l++) p[l] += hv * sWout[l * 128 + half * 64 + k];
        }
#pragma unroll
        for (int l = 0; l < 5; l++) p[l] += __shfl_down(p[l], 1);
        if (half == 0 && row < nv) {
            float lg[5], mx = -1e30f;
#pragma unroll
            for (int l = 0; l < 5; l++) {
                lg[l] = p[l] + bout[l];
                mx = fmaxf(mx, lg[l]);
            }
            float se = 0.f;
#pragma unroll
            for (int l = 0; l < 5; l++) se += __expf(lg[l] - mx);
            float lse = __logf(se) + mx;
            float* dst = lossv6 + (long)(vbase + row) * 6;
#pragma unroll
            for (int l = 0; l < 5; l++) dst[l] = lg[l];
            dst[5] = lse;
        }
    }
}

// ---------------------------------------------------------------------------
// k_level: fully fused level kernel (gemm for all 5 gates + gates + h/c write
// + per-node loss).  One block = 64 nodes.  Barrier-free direct-fragment
// K-loops (A rows / BcatT are L2/L3-resident working sets); no G intermediate.
// Wave w: rows (w&1)*32..+32, cols (w>>1)*64..+64 of each 128-col gate block.
// acc element (i,jj)[r]: row m = wrow+i*16+lquad*4+r, col j = wcol+jj*16+lrow.
// Phase order i,u,f1,f2,o keeps only {s0 (running c), acc} live at peak.
// ---------------------------------------------------------------------------
__global__ __launch_bounds__(256, 3) void k_level(
    const bf16raw* __restrict__ embeds_bf, const int* __restrict__ words,
    const int* __restrict__ labels,
    bf16raw* __restrict__ h_all, bf16raw* __restrict__ c_all,
    const bf16raw* __restrict__ hc_leaf, const float* __restrict__ lossv6,
    const bf16raw* __restrict__ BcatT, const float* __restrict__ bias_cat,
    const float* __restrict__ Wout, const float* __restrict__ bout,
    float* __restrict__ partials, float* __restrict__ out,
    int off, int nm, int leafkids, int isroot)
{
    __shared__ __align__(16) bf16raw sC[128 * 136];  // children c; reused for c/h out tiles
    __shared__ float sWout[5 * 128];

    const int t = threadIdx.x;
    const int m0 = blockIdx.x * 64;

    for (int i = t; i < 640; i += 256) sWout[i] = Wout[i];

    // ---- stage children c into sC: slot = 2*mlocal + childIdx ----
    {
        const int slot = t >> 1;              // 0..127
        const int half = (t & 1) * 64;
        int mm = slot >> 1;
        if (mm >= nm) mm = nm - 1;
        const long cg = 2L * ((long)off + m0 + mm) + 1 + (slot & 1);
        const bf16raw* src = leafkids ? (hc_leaf + (long)words[cg] * 256 + 128)
                                      : (c_all + cg * 128);
#pragma unroll
        for (int q = 0; q < 8; ++q)
            *(short8*)&sC[slot * 136 + half + q * 8] = *(const short8*)(src + half + q * 8);
    }

    const int lane = t & 63;
    const int w = t >> 6;
    const int wrow = (w & 1) * 32;
    const int wcol = (w >> 1) * 64;
    const int lrow = lane & 15;
    const int lquad = lane >> 4;

    // ---- per-lane A row pointers (2 row-frags x {x, h1, h2}) ----
    const bf16raw *axp[2], *h1p[2], *h2p[2];
#pragma unroll
    for (int i = 0; i < 2; ++i) {
        int m = wrow + i * 16 + lrow;
        if (m >= nm) m = nm - 1;               // clamp; stores masked in epilogues
        const long g = (long)off + m0 + m;
        axp[i] = embeds_bf + (long)words[g] * 128;
        if (leafkids) {
            h1p[i] = hc_leaf + (long)words[2 * g + 1] * 256;
            h2p[i] = hc_leaf + (long)words[2 * g + 2] * 256;
        } else {
            h1p[i] = h_all + (2 * g + 1) * 128;
            h2p[i] = h_all + (2 * g + 2) * 128;
        }
    }

    __syncthreads();   // sC + sWout staged

    auto run_gemm = [&](int gg, f32x4 (&acc)[2][4]) {
#pragma unroll
        for (int i = 0; i < 2; ++i)
#pragma unroll
            for (int jj = 0; jj < 4; ++jj) acc[i][jj] = (f32x4){0.f, 0.f, 0.f, 0.f};
        const bf16raw* bb = BcatT + ((long)(gg * 128 + wcol + lrow)) * 384 + lquad * 8;
#pragma unroll
        for (int kt = 0; kt < 384; kt += 32) {
            bf16x8 af[2], bfr[4];
            const int kl = (kt & 127) + lquad * 8;
#pragma unroll
            for (int i = 0; i < 2; ++i) {
                const bf16raw* p = (kt < 128) ? axp[i] : ((kt < 256) ? h1p[i] : h2p[i]);
                af[i] = *(const bf16x8*)(p + kl);
            }
#pragma unroll
            for (int jj = 0; jj < 4; ++jj)
                bfr[jj] = *(const bf16x8*)(bb + (long)jj * 16 * 384 + kt);
#pragma unroll
            for (int i = 0; i < 2; ++i)
#pragma unroll
                for (int jj = 0; jj < 4; ++jj)
                    acc[i][jj] = __builtin_amdgcn_mfma_f32_16x16x32_bf16(af[i], bfr[jj], acc[i][jj], 0, 0, 0);
        }
    };

    f32x4 acc[2][4];
    float s0[2][4][4];   // running c (then tanh(c))
    float s1[2][4][4];   // i-gate temp

    // ---- i ----
    run_gemm(0, acc);
#pragma unroll
    for (int i = 0; i < 2; ++i)
#pragma unroll
        for (int jj = 0; jj < 4; ++jj) {
            const float b = bias_cat[wcol + jj * 16 + lrow];
#pragma unroll
            for (int r = 0; r < 4; ++r) s1[i][jj][r] = sigm(acc[i][jj][r] + b);
        }
    // ---- u: s0 = i*u ----
    run_gemm(1, acc);
#pragma unroll
    for (int i = 0; i < 2; ++i)
#pragma unroll
        for (int jj = 0; jj < 4; ++jj) {
            const float b = bias_cat[128 + wcol + jj * 16 + lrow];
#pragma unroll
            for (int r = 0; r < 4; ++r) s0[i][jj][r] = s1[i][jj][r] * tanhf(acc[i][jj][r] + b);
        }
    // ---- f1: s0 += sigm(f1)*c1 ----
    run_gemm(3, acc);
#pragma unroll
    for (int i = 0; i < 2; ++i)
#pragma unroll
        for (int jj = 0; jj < 4; ++jj) {
            const float b = bias_cat[384 + wcol + jj * 16 + lrow];
#pragma unroll
            for (int r = 0; r < 4; ++r) {
                const int m = wrow + i * 16 + lquad * 4 + r;
                const int j = wcol + jj * 16 + lrow;
                s0[i][jj][r] += sigm(acc[i][jj][r] + b) * bf2f(sC[(2 * m) * 136 + j]);
            }
        }
    // ---- f2: s0 += sigm(f2)*c2 -> s0 = c ----
    run_gemm(4, acc);
#pragma unroll
    for (int i = 0; i < 2; ++i)
#pragma unroll
        for (int jj = 0; jj < 4; ++jj) {
            const float b = bias_cat[512 + wcol + jj * 16 + lrow];
#pragma unroll
            for (int r = 0; r < 4; ++r) {
                const int m = wrow + i * 16 + lquad * 4 + r;
                const int j = wcol + jj * 16 + lrow;
                s0[i][jj][r] += sigm(acc[i][jj][r] + b) * bf2f(sC[(2 * m + 1) * 136 + j]);
            }
        }
    __syncthreads();   // all sC child reads done
    // write c tile into sC, keep tanh(c) in regs
#pragma unroll
    for (int i = 0; i < 2; ++i)
#pragma unroll
        for (int jj = 0; jj < 4; ++jj)
#pragma unroll
            for (int r = 0; r < 4; ++r) {
                const int m = wrow + i * 16 + lquad * 4 + r;
                const int j = wcol + jj * 16 + lrow;
                sC[m * 136 + j] = f2bf(s0[i][jj][r]);
            }
#pragma unroll
    for (int i = 0; i < 2; ++i)
#pragma unroll
        for (int jj = 0; jj < 4; ++jj)
#pragma unroll
            for (int r = 0; r < 4; ++r) s0[i][jj][r] = tanhf(s0[i][jj][r]);
    __syncthreads();   // c tile complete
    // flush c (coalesced)
#pragma unroll
    for (int q = 0; q < 4; ++q) {
        int ci = t + 256 * q;
        int row = ci >> 4, c8 = (ci & 15) * 8;
        if (m0 + row < nm)
            *(short8*)(c_all + ((long)off + m0 + row) * 128 + c8) = *(const short8*)&sC[row * 136 + c8];
    }
    // ---- o: h = sigm(o)*tanh(c) ----
    run_gemm(2, acc);
    __syncthreads();   // flush reads of sC done before overwrite
#pragma unroll
    for (int i = 0; i < 2; ++i)
#pragma unroll
        for (int jj = 0; jj < 4; ++jj) {
            const float b = bias_cat[256 + wcol + jj * 16 + lrow];
#pragma unroll
            for (int r = 0; r < 4; ++r) {
                const int m = wrow + i * 16 + lquad * 4 + r;
                const int j = wcol + jj * 16 + lrow;
                sC[m * 136 + j] = f2bf(sigm(acc[i][jj][r] + b) * s0[i][jj][r]);
            }
        }
    __syncthreads();   // h tile complete
    // flush h (coalesced)
#pragma unroll
    for (int q = 0; q < 4; ++q) {
        int ci = t + 256 * q;
        int row = ci >> 4, c8 = (ci & 15) * 8;
        if (m0 + row < nm)
            *(short8*)(h_all + ((long)off + m0 + row) * 128 + c8) = *(const short8*)&sC[row * 136 + c8];
    }
    // ---- logits + loss: 4 threads per node row ----
    {
        const int row = t >> 2, quarter = t & 3;
        float p[5] = {0.f, 0.f, 0.f, 0.f, 0.f};
        const int kbase = quarter * 32;
        for (int k0 = 0; k0 < 32; ++k0) {
            const int k = kbase + k0;
            float hv = bf2f(sC[row * 136 + k]);
#pragma unroll
            for (int l = 0; l < 5; l++) p[l] += hv * sWout[l * 128 + k];
        }
#pragma unroll
        for (int l = 0; l < 5; l++) {
            p[l] += __shfl_down(p[l], 2);
            p[l] += __shfl_down(p[l], 1);
        }
        if (quarter == 0 && m0 + row < nm) {
            const long g = (long)off + m0 + row;
            float lg[5], mx = -1e30f;
#pragma unroll
            for (int l = 0; l < 5; l++) {
                lg[l] = p[l] + bout[l];
                mx = fmaxf(mx, lg[l]);
            }
            float se = 0.f;
#pragma unroll
            for (int l = 0; l < 5; l++) se += __expf(lg[l] - mx);
            float lse = __logf(se) + mx;
            float lossNode = lse - lg[labels[g]];
            if (leafkids) {
                const float* lv1 = lossv6 + (long)words[2 * g + 1] * 6;
                const float* lv2 = lossv6 + (long)words[2 * g + 2] * 6;
                lossNode += (lv1[5] - lv1[labels[2 * g + 1]])
                          + (lv2[5] - lv2[labels[2 * g + 2]]);
            }
            atomicAdd(&partials[(int)(g & 1023)], lossNode);
            if (isroot) {
#pragma unroll
                for (int l = 0; l < 5; l++) out[l] = lg[l] - lse;
            }
        }
    }
}

__global__ __launch_bounds__(256) void k3_reduce(const float* __restrict__ partials,
                                                 float* __restrict__ out)
{
    const int t = threadIdx.x;
    float s = 0.f;
    for (int i = t; i < 1024; i += 256) s += partials[i];
#pragma unroll
    for (int d = 32; d > 0; d >>= 1) s += __shfl_down(s, d);
    __shared__ float red[4];
    if ((t & 63) == 0) red[t >> 6] = s;
    __syncthreads();
    if (t == 0) out[5] = red[0] + red[1] + red[2] + red[3];
}

// ---------------------------------------------------------------------------
extern "C" void kernel_launch(void* const* d_in, const int* in_sizes, int n_in,
                              void* d_out, int out_size, void* d_ws, size_t ws_size,
                              hipStream_t stream)
{
    const float* embeds = (const float*)d_in[0];
    const int* words = (const int*)d_in[1];
    const int* labels = (const int*)d_in[2];
    const float* Wix = (const float*)d_in[5],  *bix  = (const float*)d_in[6];
    const float* Wih = (const float*)d_in[7],  *bih  = (const float*)d_in[8];
    const float* Wfx = (const float*)d_in[9],  *bfx  = (const float*)d_in[10];
    const float* Wfh = (const float*)d_in[11], *bfh  = (const float*)d_in[12];
    const float* Wox = (const float*)d_in[13], *box_ = (const float*)d_in[14];
    const float* Woh = (const float*)d_in[15], *boh  = (const float*)d_in[16];
    const float* Wux = (const float*)d_in[17], *bux  = (const float*)d_in[18];
    const float* Wuh = (const float*)d_in[19], *buh  = (const float*)d_in[20];
    const float* Wout = (const float*)d_in[21], *bout = (const float*)d_in[22];
    float* out = (float*)d_out;

    char* ws = (char*)d_ws;
    const size_t treeElems = (size_t)NINT * 128;
    bf16raw* h_all = (bf16raw*)ws;
    bf16raw* c_all = h_all + treeElems;
    bf16raw* embeds_bf = c_all + treeElems;
    bf16raw* BcatT = embeds_bf + (size_t)NVOCAB * 128;
    bf16raw* hc_leaf = BcatT + 640 * 384;
    float* lossv6 = (float*)(hc_leaf + (size_t)NVOCAB * 256);
    float* bias_cat = lossv6 + (size_t)NVOCAB * 6;
    float* partials = bias_cat + 640;

    k_prep_embeds<<<(NVOCAB * 128 / 4 + 255) / 256, 256, 0, stream>>>(
        embeds, embeds_bf, NVOCAB * 128 / 4);
    k_prep_bcat<<<640, 128, 0, stream>>>(Wix, bix, Wih, bih, Wfx, bfx, Wfh, bfh,
                                         Wox, box_, Woh, boh, Wux, bux, Wuh, buh,
                                         BcatT, bias_cat);
    hipMemsetAsync(partials, 0, 1024 * sizeof(float), stream);

    k_leafpre<<<(NVOCAB + 127) / 128, 256, 0, stream>>>(
        embeds_bf, BcatT, bias_cat, Wout, bout, hc_leaf, lossv6, 0, NVOCAB);

    for (int l = DEPTH - 2; l >= 0; --l) {
        const int n = 1 << l;
        const int off = n - 1;
        k_level<<<dim3((n + 63) / 64), 256, 0, stream>>>(
            embeds_bf, words, labels, h_all, c_all, hc_leaf, lossv6,
            BcatT, bias_cat, Wout, bout, partials, out,
            off, n, (l == DEPTH - 2) ? 1 : 0, (l == 0) ? 1 : 0);
    }
    k3_reduce<<<1, 256, 0, stream>>>(partials, out);
}

// Round 3
// 781.149 us; speedup vs baseline: 1.7217x; 1.7217x over previous
//
#include <hip/hip_runtime.h>
#include <math.h>

#define DEPTH 18
#define NINT ((1 << (DEPTH - 1)) - 1)   // internal nodes (h/c stored)
#define NVOCAB 50000

typedef unsigned short bf16raw;
typedef __bf16 bf16x8 __attribute__((ext_vector_type(8)));
typedef float f32x4 __attribute__((ext_vector_type(4)));
typedef short short8 __attribute__((ext_vector_type(8)));

__device__ __forceinline__ float sigm(float x) { return 1.0f / (1.0f + __expf(-x)); }

__device__ __forceinline__ float bf2f(bf16raw u) {
    union { unsigned int i; float f; } v;
    v.i = ((unsigned int)u) << 16;
    return v.f;
}
__device__ __forceinline__ bf16raw f2bf(float f) {
    union { float f; unsigned int i; } v;
    v.f = f;
    unsigned int r = v.i + 0x7FFFu + ((v.i >> 16) & 1u);  // RNE
    return (bf16raw)(r >> 16);
}

// ---------------------------------------------------------------------------
__global__ __launch_bounds__(256) void k_prep_embeds(const float* __restrict__ src,
                                                     bf16raw* __restrict__ dst, int n4)
{
    int i = blockIdx.x * blockDim.x + threadIdx.x;
    if (i < n4) {
        float4 v = ((const float4*)src)[i];
        ushort4 o;
        o.x = f2bf(v.x); o.y = f2bf(v.y); o.z = f2bf(v.z); o.w = f2bf(v.w);
        ((ushort4*)dst)[i] = o;
    }
}

// ---------------------------------------------------------------------------
// BcatT[col 0..639][k 0..383] bf16.  Gate order: 0=i, 1=u, 2=o, 3=f1, 4=f2
// ---------------------------------------------------------------------------
__global__ __launch_bounds__(128) void k_prep_bcat(
    const float* __restrict__ Wix, const float* __restrict__ bix,
    const float* __restrict__ Wih, const float* __restrict__ bih,
    const float* __restrict__ Wfx, const float* __restrict__ bfx,
    const float* __restrict__ Wfh, const float* __restrict__ bfh,
    const float* __restrict__ Wox, const float* __restrict__ box_,
    const float* __restrict__ Woh, const float* __restrict__ boh,
    const float* __restrict__ Wux, const float* __restrict__ bux,
    const float* __restrict__ Wuh, const float* __restrict__ buh,
    bf16raw* __restrict__ BcatT, float* __restrict__ bias_cat)
{
    const int j = blockIdx.x;        // 0..639
    const int grp = j >> 7, jj = j & 127;
    const float *Wx, *Wh, *bx, *bh;
    switch (grp) {
        case 0: Wx = Wix; Wh = Wih; bx = bix;  bh = bih; break;
        case 1: Wx = Wux; Wh = Wuh; bx = bux;  bh = buh; break;
        case 2: Wx = Wox; Wh = Woh; bx = box_; bh = boh; break;
        default: Wx = Wfx; Wh = Wfh; bx = bfx; bh = bfh; break;
    }
    for (int k = threadIdx.x; k < 384; k += blockDim.x) {
        float v;
        if (k < 128) {
            v = Wx[jj * 128 + k];
        } else if (k < 256) {
            v = (grp == 4) ? 0.f : Wh[jj * 128 + (k - 128)];
        } else {
            v = (grp == 3) ? 0.f : Wh[jj * 128 + (k - 256)];
        }
        BcatT[(long)j * 384 + k] = f2bf(v);
    }
    if (threadIdx.x == 0) bias_cat[j] = bx[jj] + bh[jj];
}

// ---------------------------------------------------------------------------
// k_leafpre: per-vocab leaf tables. hc_leaf[v][0..127]=h, [128..255]=c;
// lossv6[v][0..4]=logits, [5]=lse.  c-first ordering keeps one 64-reg state
// array live at a time (anti-spill).
// ---------------------------------------------------------------------------
__global__ __launch_bounds__(256, 2) void k_leafpre(
    const bf16raw* __restrict__ embeds_bf,
    const bf16raw* __restrict__ BcatT, const float* __restrict__ bias_cat,
    const float* __restrict__ Wout, const float* __restrict__ bout,
    bf16raw* __restrict__ hc_leaf, float* __restrict__ lossv6, int vbase, int nv)
{
    vbase += blockIdx.x * 128;
    nv -= vbase;
    if (nv > 128) nv = 128;
    if (nv <= 0) return;

    __shared__ __align__(16) bf16raw sA[128 * 40];
    __shared__ __align__(16) bf16raw sB[128 * 40];
    __shared__ __align__(16) bf16raw sT[128 * 136];
    __shared__ float sWout[5 * 128];

    const int t = threadIdx.x;
    for (int i = t; i < 640; i += 256) sWout[i] = Wout[i];

    const int srow = t >> 1;
    const int shalf = (t & 1) * 16;
    const int arow = (srow < nv) ? srow : 0;
    const bf16raw* ax = embeds_bf + (long)(vbase + arow) * 128;

    const int lane = t & 63;
    const int w = t >> 6;
    const int wrow = (w >> 1) * 64;
    const int wcol = (w & 1) * 64;
    const int lrow = lane & 15;
    const int lquad = lane >> 4;
    const int lkoff = lquad * 8;

    float tval[4][4][4];
    f32x4 acc[4][4];

    auto rungemm = [&](int cb) {
#pragma unroll
        for (int i = 0; i < 4; i++)
#pragma unroll
            for (int j = 0; j < 4; j++) acc[i][j] = (f32x4){0.f, 0.f, 0.f, 0.f};
        const bf16raw* bsrc = BcatT + ((long)(cb * 128 + srow)) * 384;
        for (int kt = 0; kt < 128; kt += 32) {
            short8 av0 = *(const short8*)(ax + kt + shalf);
            short8 av1 = *(const short8*)(ax + kt + shalf + 8);
            short8 bv0 = *(const short8*)(bsrc + kt + shalf);
            short8 bv1 = *(const short8*)(bsrc + kt + shalf + 8);
            __syncthreads();
            *(short8*)&sA[srow * 40 + shalf] = av0;
            *(short8*)&sA[srow * 40 + shalf + 8] = av1;
            *(short8*)&sB[srow * 40 + shalf] = bv0;
            *(short8*)&sB[srow * 40 + shalf + 8] = bv1;
            __syncthreads();
            bf16x8 af[4], bfr[4];
#pragma unroll
            for (int i = 0; i < 4; i++) {
                af[i]  = *(const bf16x8*)&sA[(wrow + i * 16 + lrow) * 40 + lkoff];
                bfr[i] = *(const bf16x8*)&sB[(wcol + i * 16 + lrow) * 40 + lkoff];
            }
#pragma unroll
            for (int i = 0; i < 4; i++)
#pragma unroll
                for (int j = 0; j < 4; j++)
                    acc[i][j] = __builtin_amdgcn_mfma_f32_16x16x32_bf16(af[i], bfr[j], acc[i][j], 0, 0, 0);
        }
    };

    // ---- i gate ----
    rungemm(0);
#pragma unroll
    for (int i = 0; i < 4; i++)
#pragma unroll
        for (int jj = 0; jj < 4; jj++) {
            const float b = bias_cat[wcol + jj * 16 + lrow];
#pragma unroll
            for (int r = 0; r < 4; r++) tval[i][jj][r] = sigm(acc[i][jj][r] + b);
        }
    // ---- u gate: tval = c = i*u ----
    rungemm(1);
#pragma unroll
    for (int i = 0; i < 4; i++)
#pragma unroll
        for (int jj = 0; jj < 4; jj++) {
            const float b = bias_cat[128 + wcol + jj * 16 + lrow];
#pragma unroll
            for (int r = 0; r < 4; r++) tval[i][jj][r] *= tanhf(acc[i][jj][r] + b);
        }
    // write c tile, then keep tanh(c) in regs
#pragma unroll
    for (int i = 0; i < 4; i++)
#pragma unroll
        for (int jj = 0; jj < 4; jj++)
#pragma unroll
            for (int r = 0; r < 4; r++) {
                const int m = wrow + i * 16 + lquad * 4 + r;
                const int j = wcol + jj * 16 + lrow;
                sT[m * 136 + j] = f2bf(tval[i][jj][r]);
            }
#pragma unroll
    for (int i = 0; i < 4; i++)
#pragma unroll
        for (int jj = 0; jj < 4; jj++)
#pragma unroll
            for (int r = 0; r < 4; r++) tval[i][jj][r] = tanhf(tval[i][jj][r]);
    __syncthreads();
    // flush c to hc_leaf[.., 128..255]
#pragma unroll
    for (int s = 0; s < 8; ++s) {
        int ci = t + 256 * s;
        int row = ci >> 4, c8 = (ci & 15) * 8;
        if (row < nv)
            *(short8*)(hc_leaf + (long)(vbase + row) * 256 + 128 + c8) = *(const short8*)&sT[row * 136 + c8];
    }
    // ---- o gate: h = sigm(o) * tanh(c) ----
    rungemm(2);
    __syncthreads();
#pragma unroll
    for (int i = 0; i < 4; i++)
#pragma unroll
        for (int jj = 0; jj < 4; jj++) {
            const float b = bias_cat[256 + wcol + jj * 16 + lrow];
#pragma unroll
            for (int r = 0; r < 4; r++) {
                const int m = wrow + i * 16 + lquad * 4 + r;
                const int j = wcol + jj * 16 + lrow;
                sT[m * 136 + j] = f2bf(sigm(acc[i][jj][r] + b) * tval[i][jj][r]);
            }
        }
    __syncthreads();
    // flush h to hc_leaf[.., 0..127]
#pragma unroll
    for (int s = 0; s < 8; ++s) {
        int ci = t + 256 * s;
        int row = ci >> 4, c8 = (ci & 15) * 8;
        if (row < nv)
            *(short8*)(hc_leaf + (long)(vbase + row) * 256 + c8) = *(const short8*)&sT[row * 136 + c8];
    }
    // logits + lse per vocab row
    {
        const int row = t >> 1, half = t & 1;
        float p[5] = {0.f, 0.f, 0.f, 0.f, 0.f};
        for (int k = 0; k < 64; ++k) {
            float hv = bf2f(sT[row * 136 + half * 64 + k]);
#pragma unroll
            for (int l = 0; l < 5; l++) p[l] += hv * sWout[l * 128 + half * 64 + k];
        }
#pragma unroll
        for (int l = 0; l < 5; l++) p[l] += __shfl_down(p[l], 1);
        if (half == 0 && row < nv) {
            float lg[5], mx = -1e30f;
#pragma unroll
            for (int l = 0; l < 5; l++) {
                lg[l] = p[l] + bout[l];
                mx = fmaxf(mx, lg[l]);
            }
            float se = 0.f;
#pragma unroll
            for (int l = 0; l < 5; l++) se += __expf(lg[l] - mx);
            float lse = __logf(se) + mx;
            float* dst = lossv6 + (long)(vbase + row) * 6;
#pragma unroll
            for (int l = 0; l < 5; l++) dst[l] = lg[l];
            dst[5] = lse;
        }
    }
}

// ---------------------------------------------------------------------------
// k_level32: fused level kernel, anti-spill design.
//  - block = 32 nodes, 256 threads (4 waves).
//  - A tile (32 x 384 = x|h1|h2) staged ONCE into LDS (8 thr/row x 6 short8,
//    full coverage); children c staged into LDS (4 thr/slot x 4 short8);
//    after one barrier the whole 5-gate K-loop is barrier-free.
//  - B fragments read directly from global: BcatT (480 KB) is identical for
//    every block -> L2-broadcast; loads pipeline under MFMA.
//  - Wave w owns cols [w*32, w*32+32) WITHIN EACH gate: acc[5][2][2]
//    (80 VGPRs) holds i,u,o,f1,f2 for the same (row,col) patch; gate math
//    combines entirely in-register (accumulators ARE the carried state).
// acc element (i,jj)[r]: local row m = i*16 + lquad*4 + r,
//                        gate-col j = w*32 + jj*16 + lrow.
// ---------------------------------------------------------------------------
__global__ __launch_bounds__(256, 2) void k_level32(
    const bf16raw* __restrict__ embeds_bf, const int* __restrict__ words,
    const int* __restrict__ labels,
    bf16raw* __restrict__ h_all, bf16raw* __restrict__ c_all,
    const bf16raw* __restrict__ hc_leaf, const float* __restrict__ lossv6,
    const bf16raw* __restrict__ BcatT, const float* __restrict__ bias_cat,
    const float* __restrict__ Wout, const float* __restrict__ bout,
    float* __restrict__ partials, float* __restrict__ out,
    int off, int nm, int leafkids, int isroot)
{
    __shared__ __align__(16) bf16raw sA[32 * 392];    // A tile, row stride 392 (16B-aligned)
    __shared__ __align__(16) bf16raw sCT[64 * 136];   // children c (64 slots); reused as c/h out tiles
    __shared__ float sWout[640];

    const int t = threadIdx.x;
    const int m0 = blockIdx.x * 32;

    for (int i = t; i < 640; i += 256) sWout[i] = Wout[i];

    // ---- stage A tile: 8 threads per row; each thread 6 short8 (full cover) ----
    {
        const int row = t >> 3;            // 0..31
        const int co = (t & 7) * 8;        // 0..56, 16B chunks
        int mm = m0 + row; if (mm >= nm) mm = nm - 1;
        const long g = (long)off + mm;
        const bf16raw* px = embeds_bf + (long)words[g] * 128;
        const bf16raw *p1, *p2;
        if (leafkids) {
            p1 = hc_leaf + (long)words[2 * g + 1] * 256;
            p2 = hc_leaf + (long)words[2 * g + 2] * 256;
        } else {
            p1 = h_all + (2 * g + 1) * 128;
            p2 = h_all + (2 * g + 2) * 128;
        }
        *(short8*)&sA[row * 392 + co]            = *(const short8*)(px + co);
        *(short8*)&sA[row * 392 + 64 + co]       = *(const short8*)(px + 64 + co);
        *(short8*)&sA[row * 392 + 128 + co]      = *(const short8*)(p1 + co);
        *(short8*)&sA[row * 392 + 192 + co]      = *(const short8*)(p1 + 64 + co);
        *(short8*)&sA[row * 392 + 256 + co]      = *(const short8*)(p2 + co);
        *(short8*)&sA[row * 392 + 320 + co]      = *(const short8*)(p2 + 64 + co);
    }
    // ---- stage children c: slot = 2*mlocal + childIdx; 4 thr/slot x 4 short8 ----
    {
        const int slot = t >> 2;           // 0..63
        const int cc = (t & 3) * 8;        // 0..24
        int mm = m0 + (slot >> 1); if (mm >= nm) mm = nm - 1;
        const long g = (long)off + mm;
        const long cg = 2 * g + 1 + (slot & 1);
        const bf16raw* pc = leafkids ? (hc_leaf + (long)words[cg] * 256 + 128)
                                     : (c_all + cg * 128);
#pragma unroll
        for (int s = 0; s < 4; ++s)
            *(short8*)&sCT[slot * 136 + s * 32 + cc] = *(const short8*)(pc + s * 32 + cc);
    }

    const int lane = t & 63;
    const int w = t >> 6;
    const int lrow = lane & 15;
    const int lquad = lane >> 4;

    __syncthreads();   // A tile, children, sWout staged

    // ---- 5-gate GEMM, barrier-free ----
    f32x4 acc[5][2][2];
#pragma unroll
    for (int g = 0; g < 5; ++g)
#pragma unroll
        for (int i = 0; i < 2; ++i)
#pragma unroll
            for (int jj = 0; jj < 2; ++jj) acc[g][i][jj] = (f32x4){0.f, 0.f, 0.f, 0.f};

    const bf16raw* bb = BcatT + ((long)(w * 32 + lrow)) * 384 + lquad * 8;
    for (int kt = 0; kt < 384; kt += 32) {
        bf16x8 af[2];
#pragma unroll
        for (int i = 0; i < 2; ++i)
            af[i] = *(const bf16x8*)&sA[(i * 16 + lrow) * 392 + kt + lquad * 8];
#pragma unroll
        for (int g = 0; g < 5; ++g)
#pragma unroll
            for (int jj = 0; jj < 2; ++jj) {
                bf16x8 bfr = *(const bf16x8*)(bb + (long)((g * 128 + jj * 16) * 384) + kt);
#pragma unroll
                for (int i = 0; i < 2; ++i)
                    acc[g][i][jj] = __builtin_amdgcn_mfma_f32_16x16x32_bf16(af[i], bfr, acc[g][i][jj], 0, 0, 0);
            }
    }

    // ---- gate math fully in-register (reads children from sCT) ----
    float cv[2][2][4], hv[2][2][4];
#pragma unroll
    for (int i = 0; i < 2; ++i)
#pragma unroll
        for (int jj = 0; jj < 2; ++jj) {
            const int j = w * 32 + jj * 16 + lrow;
            const float bi = bias_cat[j];
            const float bu = bias_cat[128 + j];
            const float bo = bias_cat[256 + j];
            const float b1 = bias_cat[384 + j];
            const float b2 = bias_cat[512 + j];
#pragma unroll
            for (int r = 0; r < 4; ++r) {
                const int m = i * 16 + lquad * 4 + r;
                const float c1 = bf2f(sCT[(2 * m) * 136 + j]);
                const float c2 = bf2f(sCT[(2 * m + 1) * 136 + j]);
                const float iv = sigm(acc[0][i][jj][r] + bi);
                const float uv = tanhf(acc[1][i][jj][r] + bu);
                const float ov = sigm(acc[2][i][jj][r] + bo);
                const float f1 = sigm(acc[3][i][jj][r] + b1);
                const float f2 = sigm(acc[4][i][jj][r] + b2);
                const float c = iv * uv + f1 * c1 + f2 * c2;
                cv[i][jj][r] = c;
                hv[i][jj][r] = ov * tanhf(c);
            }
        }
    __syncthreads();   // all child reads complete before overwriting sCT

    // ---- write c (rows 0..31) and h (rows 32..63) tiles ----
#pragma unroll
    for (int i = 0; i < 2; ++i)
#pragma unroll
        for (int jj = 0; jj < 2; ++jj) {
            const int j = w * 32 + jj * 16 + lrow;
#pragma unroll
            for (int r = 0; r < 4; ++r) {
                const int m = i * 16 + lquad * 4 + r;
                sCT[m * 136 + j] = f2bf(cv[i][jj][r]);
                sCT[(32 + m) * 136 + j] = f2bf(hv[i][jj][r]);
            }
        }
    __syncthreads();

    // ---- coalesced flush: rows 0..31 -> c_all, rows 32..63 -> h_all ----
#pragma unroll
    for (int q = 0; q < 4; ++q) {
        int ci = t + 256 * q;               // 0..1023
        int row = ci >> 4;                  // 0..63
        int c8 = (ci & 15) * 8;
        int m = row & 31;
        if (m0 + m < nm) {
            bf16raw* dst = (row < 32) ? c_all : h_all;
            *(short8*)(dst + ((long)off + m0 + m) * 128 + c8) = *(const short8*)&sCT[row * 136 + c8];
        }
    }

    // ---- logits + loss: 8 threads per node ----
    {
        const int row = t >> 3, oct = t & 7;
        float p[5] = {0.f, 0.f, 0.f, 0.f, 0.f};
#pragma unroll
        for (int k0 = 0; k0 < 16; ++k0) {
            const int k = oct * 16 + k0;
            float hval = bf2f(sCT[(32 + row) * 136 + k]);
#pragma unroll
            for (int l = 0; l < 5; l++) p[l] += hval * sWout[l * 128 + k];
        }
#pragma unroll
        for (int l = 0; l < 5; l++) {
            p[l] += __shfl_down(p[l], 4);
            p[l] += __shfl_down(p[l], 2);
            p[l] += __shfl_down(p[l], 1);
        }
        if (oct == 0 && m0 + row < nm) {
            const long g = (long)off + m0 + row;
            float lg[5], mx = -1e30f;
#pragma unroll
            for (int l = 0; l < 5; l++) {
                lg[l] = p[l] + bout[l];
                mx = fmaxf(mx, lg[l]);
            }
            float se = 0.f;
#pragma unroll
            for (int l = 0; l < 5; l++) se += __expf(lg[l] - mx);
            float lse = __logf(se) + mx;
            float lossNode = lse - lg[labels[g]];
            if (leafkids) {
                const float* lv1 = lossv6 + (long)words[2 * g + 1] * 6;
                const float* lv2 = lossv6 + (long)words[2 * g + 2] * 6;
                lossNode += (lv1[5] - lv1[labels[2 * g + 1]])
                          + (lv2[5] - lv2[labels[2 * g + 2]]);
            }
            atomicAdd(&partials[(int)(g & 1023)], lossNode);
            if (isroot) {
#pragma unroll
                for (int l = 0; l < 5; l++) out[l] = lg[l] - lse;
            }
        }
    }
}

__global__ __launch_bounds__(256) void k3_reduce(const float* __restrict__ partials,
                                                 float* __restrict__ out)
{
    const int t = threadIdx.x;
    float s = 0.f;
    for (int i = t; i < 1024; i += 256) s += partials[i];
#pragma unroll
    for (int d = 32; d > 0; d >>= 1) s += __shfl_down(s, d);
    __shared__ float red[4];
    if ((t & 63) == 0) red[t >> 6] = s;
    __syncthreads();
    if (t == 0) out[5] = red[0] + red[1] + red[2] + red[3];
}

// ---------------------------------------------------------------------------
extern "C" void kernel_launch(void* const* d_in, const int* in_sizes, int n_in,
                              void* d_out, int out_size, void* d_ws, size_t ws_size,
                              hipStream_t stream)
{
    const float* embeds = (const float*)d_in[0];
    const int* words = (const int*)d_in[1];
    const int* labels = (const int*)d_in[2];
    const float* Wix = (const float*)d_in[5],  *bix  = (const float*)d_in[6];
    const float* Wih = (const float*)d_in[7],  *bih  = (const float*)d_in[8];
    const float* Wfx = (const float*)d_in[9],  *bfx  = (const float*)d_in[10];
    const float* Wfh = (const float*)d_in[11], *bfh  = (const float*)d_in[12];
    const float* Wox = (const float*)d_in[13], *box_ = (const float*)d_in[14];
    const float* Woh = (const float*)d_in[15], *boh  = (const float*)d_in[16];
    const float* Wux = (const float*)d_in[17], *bux  = (const float*)d_in[18];
    const float* Wuh = (const float*)d_in[19], *buh  = (const float*)d_in[20];
    const float* Wout = (const float*)d_in[21], *bout = (const float*)d_in[22];
    float* out = (float*)d_out;

    char* ws = (char*)d_ws;
    const size_t treeElems = (size_t)NINT * 128;
    bf16raw* h_all = (bf16raw*)ws;
    bf16raw* c_all = h_all + treeElems;
    bf16raw* embeds_bf = c_all + treeElems;
    bf16raw* BcatT = embeds_bf + (size_t)NVOCAB * 128;
    bf16raw* hc_leaf = BcatT + 640 * 384;
    float* lossv6 = (float*)(hc_leaf + (size_t)NVOCAB * 256);
    float* bias_cat = lossv6 + (size_t)NVOCAB * 6;
    float* partials = bias_cat + 640;

    k_prep_embeds<<<(NVOCAB * 128 / 4 + 255) / 256, 256, 0, stream>>>(
        embeds, embeds_bf, NVOCAB * 128 / 4);
    k_prep_bcat<<<640, 128, 0, stream>>>(Wix, bix, Wih, bih, Wfx, bfx, Wfh, bfh,
                                         Wox, box_, Woh, boh, Wux, bux, Wuh, buh,
                                         BcatT, bias_cat);
    hipMemsetAsync(partials, 0, 1024 * sizeof(float), stream);

    k_leafpre<<<(NVOCAB + 127) / 128, 256, 0, stream>>>(
        embeds_bf, BcatT, bias_cat, Wout, bout, hc_leaf, lossv6, 0, NVOCAB);

    for (int l = DEPTH - 2; l >= 0; --l) {
        const int n = 1 << l;
        const int off = n - 1;
        k_level32<<<dim3((n + 31) / 32), 256, 0, stream>>>(
            embeds_bf, words, labels, h_all, c_all, hc_leaf, lossv6,
            BcatT, bias_cat, Wout, bout, partials, out,
            off, n, (l == DEPTH - 2) ? 1 : 0, (l == 0) ? 1 : 0);
    }
    k3_reduce<<<1, 256, 0, stream>>>(partials, out);
}

// Round 4
// 611.427 us; speedup vs baseline: 2.1996x; 1.2776x over previous
//
#include <hip/hip_runtime.h>
#include <math.h>

#define DEPTH 18
#define NINT ((1 << (DEPTH - 1)) - 1)   // internal nodes (h/c stored)
#define NVOCAB 50000

typedef unsigned short bf16raw;
typedef __bf16 bf16x8 __attribute__((ext_vector_type(8)));
typedef float f32x4 __attribute__((ext_vector_type(4)));
typedef short short8 __attribute__((ext_vector_type(8)));

__device__ __forceinline__ float sigm(float x) { return 1.0f / (1.0f + __expf(-x)); }

__device__ __forceinline__ float bf2f(bf16raw u) {
    union { unsigned int i; float f; } v;
    v.i = ((unsigned int)u) << 16;
    return v.f;
}
__device__ __forceinline__ bf16raw f2bf(float f) {
    union { float f; unsigned int i; } v;
    v.f = f;
    unsigned int r = v.i + 0x7FFFu + ((v.i >> 16) & 1u);  // RNE
    return (bf16raw)(r >> 16);
}

// ---------------------------------------------------------------------------
__global__ __launch_bounds__(256) void k_prep_embeds(const float* __restrict__ src,
                                                     bf16raw* __restrict__ dst, int n4)
{
    int i = blockIdx.x * blockDim.x + threadIdx.x;
    if (i < n4) {
        float4 v = ((const float4*)src)[i];
        ushort4 o;
        o.x = f2bf(v.x); o.y = f2bf(v.y); o.z = f2bf(v.z); o.w = f2bf(v.w);
        ((ushort4*)dst)[i] = o;
    }
}

// ---------------------------------------------------------------------------
// Bfrag: fragment-linear B.  Gate order: 0=i, 1=u, 2=o, 3=f1, 4=f2.
// Logical B = BcatT[col 0..639][k 0..383] (col j of gate g = W row j&127;
// k<128 -> Wx, 128..255 -> Wh(child1), 256..383 -> Wh(child2); f1 zero for
// k>=256, f2 zero for k in [128,256)).
// Physical: Bfrag[((tile*12 + ktile)*64 + lane)*8 + e] where tile=col>>4,
// lane = ((k>>3)&3)*16 + (col&15), ktile=k>>5, e=k&7.  A wave loading one
// MFMA B fragment reads 64 consecutive 16B chunks -> one coalesced 1KB txn.
// ---------------------------------------------------------------------------
__global__ __launch_bounds__(128) void k_prep_bcat(
    const float* __restrict__ Wix, const float* __restrict__ bix,
    const float* __restrict__ Wih, const float* __restrict__ bih,
    const float* __restrict__ Wfx, const float* __restrict__ bfx,
    const float* __restrict__ Wfh, const float* __restrict__ bfh,
    const float* __restrict__ Wox, const float* __restrict__ box_,
    const float* __restrict__ Woh, const float* __restrict__ boh,
    const float* __restrict__ Wux, const float* __restrict__ bux,
    const float* __restrict__ Wuh, const float* __restrict__ buh,
    bf16raw* __restrict__ Bfrag, float* __restrict__ bias_cat)
{
    const int j = blockIdx.x;        // 0..639
    const int grp = j >> 7, jj = j & 127;
    const float *Wx, *Wh, *bx, *bh;
    switch (grp) {
        case 0: Wx = Wix; Wh = Wih; bx = bix;  bh = bih; break;
        case 1: Wx = Wux; Wh = Wuh; bx = bux;  bh = buh; break;
        case 2: Wx = Wox; Wh = Woh; bx = box_; bh = boh; break;
        default: Wx = Wfx; Wh = Wfh; bx = bfx; bh = bfh; break;
    }
    const int tile = j >> 4, lr = j & 15;
    for (int k = threadIdx.x; k < 384; k += blockDim.x) {
        float v;
        if (k < 128) {
            v = Wx[jj * 128 + k];
        } else if (k < 256) {
            v = (grp == 4) ? 0.f : Wh[jj * 128 + (k - 128)];
        } else {
            v = (grp == 3) ? 0.f : Wh[jj * 128 + (k - 256)];
        }
        const int idx = ((tile * 12 + (k >> 5)) * 64 + ((k >> 3) & 3) * 16 + lr) * 8 + (k & 7);
        Bfrag[idx] = f2bf(v);
    }
    if (threadIdx.x == 0) bias_cat[j] = bx[jj] + bh[jj];
}

// ---------------------------------------------------------------------------
// k_leafpre: per-vocab leaf tables. hc_leaf[v][0..127]=h, [128..255]=c;
// lossv6[v][0..4]=logits, [5]=lse.
// A (128x128 embeds tile) staged ONCE in LDS; B via coalesced Bfrag loads
// (L2-resident); K-loop fully barrier-free.  c-first ordering keeps one
// 64-reg state array live at a time.
// ---------------------------------------------------------------------------
__global__ __launch_bounds__(256, 2) void k_leafpre(
    const bf16raw* __restrict__ embeds_bf,
    const bf16raw* __restrict__ Bfrag, const float* __restrict__ bias_cat,
    const float* __restrict__ Wout, const float* __restrict__ bout,
    bf16raw* __restrict__ hc_leaf, float* __restrict__ lossv6, int vbase, int nv)
{
    vbase += blockIdx.x * 128;
    nv -= vbase;
    if (nv > 128) nv = 128;
    if (nv <= 0) return;

    __shared__ __align__(16) bf16raw sA[128 * 136];
    __shared__ __align__(16) bf16raw sT[128 * 136];
    __shared__ float sWout[5 * 128];

    const int t = threadIdx.x;
    for (int i = t; i < 640; i += 256) sWout[i] = Wout[i];

    // ---- stage full A tile once: 2 threads/row x 8 short8 ----
    {
        const int row = t >> 1;
        const int half = (t & 1) * 64;
        const int arow = (row < nv) ? row : 0;
        const bf16raw* ax = embeds_bf + (long)(vbase + arow) * 128;
#pragma unroll
        for (int s = 0; s < 8; ++s)
            *(short8*)&sA[row * 136 + half + s * 8] = *(const short8*)(ax + half + s * 8);
    }

    const int lane = t & 63;
    const int w = t >> 6;
    const int wrow = (w >> 1) * 64;
    const int wcol = (w & 1) * 64;
    const int lrow = lane & 15;
    const int lquad = lane >> 4;

    __syncthreads();

    const bf16raw* bfbase = Bfrag + (long)lane * 8;

    float tval[4][4][4];
    f32x4 acc[4][4];

    auto rungemm = [&](int cb) {
#pragma unroll
        for (int i = 0; i < 4; i++)
#pragma unroll
            for (int j = 0; j < 4; j++) acc[i][j] = (f32x4){0.f, 0.f, 0.f, 0.f};
        for (int kt = 0; kt < 128; kt += 32) {
            bf16x8 af[4], bfr[4];
#pragma unroll
            for (int i = 0; i < 4; i++)
                af[i] = *(const bf16x8*)&sA[(wrow + i * 16 + lrow) * 136 + kt + lquad * 8];
#pragma unroll
            for (int j = 0; j < 4; j++)
                bfr[j] = *(const bf16x8*)(bfbase +
                        (long)(((cb * 8 + (wcol >> 4) + j) * 12 + (kt >> 5)) * 512));
#pragma unroll
            for (int i = 0; i < 4; i++)
#pragma unroll
                for (int j = 0; j < 4; j++)
                    acc[i][j] = __builtin_amdgcn_mfma_f32_16x16x32_bf16(af[i], bfr[j], acc[i][j], 0, 0, 0);
        }
    };

    // ---- i gate ----
    rungemm(0);
#pragma unroll
    for (int i = 0; i < 4; i++)
#pragma unroll
        for (int jj = 0; jj < 4; jj++) {
            const float b = bias_cat[wcol + jj * 16 + lrow];
#pragma unroll
            for (int r = 0; r < 4; r++) tval[i][jj][r] = sigm(acc[i][jj][r] + b);
        }
    // ---- u gate: tval = c = i*u ----
    rungemm(1);
#pragma unroll
    for (int i = 0; i < 4; i++)
#pragma unroll
        for (int jj = 0; jj < 4; jj++) {
            const float b = bias_cat[128 + wcol + jj * 16 + lrow];
#pragma unroll
            for (int r = 0; r < 4; r++) tval[i][jj][r] *= tanhf(acc[i][jj][r] + b);
        }
    // write c tile, then keep tanh(c) in regs
#pragma unroll
    for (int i = 0; i < 4; i++)
#pragma unroll
        for (int jj = 0; jj < 4; jj++)
#pragma unroll
            for (int r = 0; r < 4; r++) {
                const int m = wrow + i * 16 + lquad * 4 + r;
                const int j = wcol + jj * 16 + lrow;
                sT[m * 136 + j] = f2bf(tval[i][jj][r]);
            }
#pragma unroll
    for (int i = 0; i < 4; i++)
#pragma unroll
        for (int jj = 0; jj < 4; jj++)
#pragma unroll
            for (int r = 0; r < 4; r++) tval[i][jj][r] = tanhf(tval[i][jj][r]);
    __syncthreads();
    // flush c to hc_leaf[.., 128..255]
#pragma unroll
    for (int s = 0; s < 8; ++s) {
        int ci = t + 256 * s;
        int row = ci >> 4, c8 = (ci & 15) * 8;
        if (row < nv)
            *(short8*)(hc_leaf + (long)(vbase + row) * 256 + 128 + c8) = *(const short8*)&sT[row * 136 + c8];
    }
    // ---- o gate: h = sigm(o) * tanh(c) ----
    rungemm(2);
    __syncthreads();
#pragma unroll
    for (int i = 0; i < 4; i++)
#pragma unroll
        for (int jj = 0; jj < 4; jj++) {
            const float b = bias_cat[256 + wcol + jj * 16 + lrow];
#pragma unroll
            for (int r = 0; r < 4; r++) {
                const int m = wrow + i * 16 + lquad * 4 + r;
                const int j = wcol + jj * 16 + lrow;
                sT[m * 136 + j] = f2bf(sigm(acc[i][jj][r] + b) * tval[i][jj][r]);
            }
        }
    __syncthreads();
    // flush h to hc_leaf[.., 0..127]
#pragma unroll
    for (int s = 0; s < 8; ++s) {
        int ci = t + 256 * s;
        int row = ci >> 4, c8 = (ci & 15) * 8;
        if (row < nv)
            *(short8*)(hc_leaf + (long)(vbase + row) * 256 + c8) = *(const short8*)&sT[row * 136 + c8];
    }
    // logits + lse per vocab row
    {
        const int row = t >> 1, half = t & 1;
        float p[5] = {0.f, 0.f, 0.f, 0.f, 0.f};
        for (int k = 0; k < 64; ++k) {
            float hv = bf2f(sT[row * 136 + half * 64 + k]);
#pragma unroll
            for (int l = 0; l < 5; l++) p[l] += hv * sWout[l * 128 + half * 64 + k];
        }
#pragma unroll
        for (int l = 0; l < 5; l++) p[l] += __shfl_down(p[l], 1);
        if (half == 0 && row < nv) {
            float lg[5], mx = -1e30f;
#pragma unroll
            for (int l = 0; l < 5; l++) {
                lg[l] = p[l] + bout[l];
                mx = fmaxf(mx, lg[l]);
            }
            float se = 0.f;
#pragma unroll
            for (int l = 0; l < 5; l++) se += __expf(lg[l] - mx);
            float lse = __logf(se) + mx;
            float* dst = lossv6 + (long)(vbase + row) * 6;
#pragma unroll
            for (int l = 0; l < 5; l++) dst[l] = lg[l];
            dst[5] = lse;
        }
    }
}

// ---------------------------------------------------------------------------
// k_level32: fused level kernel (5-gate GEMM + gate math + h/c + loss).
//  - block = 32 nodes, 256 threads (4 waves), ~45 KB LDS -> 3 blocks/CU.
//  - A tile staged once in LDS; children c staged in LDS; one barrier, then
//    the whole 5-gate K-loop is barrier-free.
//  - B via COALESCED Bfrag loads (fragment-linear layout, L2-resident):
//    one wave-load = 1KB contiguous, fixing the round-3 64-lines-per-instr
//    gather that left MfmaUtil at 8%.
//  - zero-block skip: f1 skips k>=256, f2 skips k in [128,256) (13% less).
//  - Wave w owns cols [w*32, w*32+32) of each gate; acc[5][2][2] holds all
//    five gates for the same (row,col) patch -> gate math in-register.
// acc element (g,i,jj)[r]: local row m = i*16 + lquad*4 + r,
//                          gate-col j = w*32 + jj*16 + lrow.
// ---------------------------------------------------------------------------
__global__ __launch_bounds__(256, 3) void k_level32(
    const bf16raw* __restrict__ embeds_bf, const int* __restrict__ words,
    const int* __restrict__ labels,
    bf16raw* __restrict__ h_all, bf16raw* __restrict__ c_all,
    const bf16raw* __restrict__ hc_leaf, const float* __restrict__ lossv6,
    const bf16raw* __restrict__ Bfrag, const float* __restrict__ bias_cat,
    const float* __restrict__ Wout, const float* __restrict__ bout,
    float* __restrict__ partials, float* __restrict__ out,
    int off, int nm, int leafkids, int isroot)
{
    __shared__ __align__(16) bf16raw sA[32 * 392];    // A tile, row stride 392
    __shared__ __align__(16) bf16raw sCT[64 * 136];   // children c; reused as c/h out tiles
    __shared__ float sWout[640];

    const int t = threadIdx.x;
    const int m0 = blockIdx.x * 32;

    for (int i = t; i < 640; i += 256) sWout[i] = Wout[i];

    // ---- stage A tile: 8 threads per row; each thread 6 short8 (full cover) ----
    {
        const int row = t >> 3;            // 0..31
        const int co = (t & 7) * 8;        // 0..56, 16B chunks
        int mm = m0 + row; if (mm >= nm) mm = nm - 1;
        const long g = (long)off + mm;
        const bf16raw* px = embeds_bf + (long)words[g] * 128;
        const bf16raw *p1, *p2;
        if (leafkids) {
            p1 = hc_leaf + (long)words[2 * g + 1] * 256;
            p2 = hc_leaf + (long)words[2 * g + 2] * 256;
        } else {
            p1 = h_all + (2 * g + 1) * 128;
            p2 = h_all + (2 * g + 2) * 128;
        }
        *(short8*)&sA[row * 392 + co]            = *(const short8*)(px + co);
        *(short8*)&sA[row * 392 + 64 + co]       = *(const short8*)(px + 64 + co);
        *(short8*)&sA[row * 392 + 128 + co]      = *(const short8*)(p1 + co);
        *(short8*)&sA[row * 392 + 192 + co]      = *(const short8*)(p1 + 64 + co);
        *(short8*)&sA[row * 392 + 256 + co]      = *(const short8*)(p2 + co);
        *(short8*)&sA[row * 392 + 320 + co]      = *(const short8*)(p2 + 64 + co);
    }
    // ---- stage children c: slot = 2*mlocal + childIdx; 4 thr/slot x 4 short8 ----
    {
        const int slot = t >> 2;           // 0..63
        const int cc = (t & 3) * 8;        // 0..24
        int mm = m0 + (slot >> 1); if (mm >= nm) mm = nm - 1;
        const long g = (long)off + mm;
        const long cg = 2 * g + 1 + (slot & 1);
        const bf16raw* pc = leafkids ? (hc_leaf + (long)words[cg] * 256 + 128)
                                     : (c_all + cg * 128);
#pragma unroll
        for (int s = 0; s < 4; ++s)
            *(short8*)&sCT[slot * 136 + s * 32 + cc] = *(const short8*)(pc + s * 32 + cc);
    }

    const int lane = t & 63;
    const int w = t >> 6;
    const int lrow = lane & 15;
    const int lquad = lane >> 4;

    __syncthreads();   // A tile, children, sWout staged

    // ---- 5-gate GEMM, barrier-free, coalesced B ----
    f32x4 acc[5][2][2];
#pragma unroll
    for (int g = 0; g < 5; ++g)
#pragma unroll
        for (int i = 0; i < 2; ++i)
#pragma unroll
            for (int jj = 0; jj < 2; ++jj) acc[g][i][jj] = (f32x4){0.f, 0.f, 0.f, 0.f};

    const bf16raw* bfbase = Bfrag + (long)lane * 8;

    auto kchunk = [&](int kt, unsigned gmask) {
        bf16x8 af[2];
#pragma unroll
        for (int i = 0; i < 2; ++i)
            af[i] = *(const bf16x8*)&sA[(i * 16 + lrow) * 392 + kt + lquad * 8];
        const int ktile = kt >> 5;
#pragma unroll
        for (int g = 0; g < 5; ++g) {
            if (!((gmask >> g) & 1)) continue;
#pragma unroll
            for (int jj = 0; jj < 2; ++jj) {
                bf16x8 bfr = *(const bf16x8*)(bfbase +
                        (long)(((g * 8 + w * 2 + jj) * 12 + ktile) * 512));
#pragma unroll
                for (int i = 0; i < 2; ++i)
                    acc[g][i][jj] = __builtin_amdgcn_mfma_f32_16x16x32_bf16(af[i], bfr, acc[g][i][jj], 0, 0, 0);
            }
        }
    };
    for (int kt = 0; kt < 128; kt += 32) kchunk(kt, 0x1Fu);        // x: all gates
    for (int kt = 128; kt < 256; kt += 32) kchunk(kt, 0x0Fu);      // h1: skip f2
    for (int kt = 256; kt < 384; kt += 32) kchunk(kt, 0x17u);      // h2: skip f1

    // ---- gate math fully in-register (reads children from sCT) ----
    float cv[2][2][4], hv[2][2][4];
#pragma unroll
    for (int i = 0; i < 2; ++i)
#pragma unroll
        for (int jj = 0; jj < 2; ++jj) {
            const int j = w * 32 + jj * 16 + lrow;
            const float bi = bias_cat[j];
            const float bu = bias_cat[128 + j];
            const float bo = bias_cat[256 + j];
            const float b1 = bias_cat[384 + j];
            const float b2 = bias_cat[512 + j];
#pragma unroll
            for (int r = 0; r < 4; ++r) {
                const int m = i * 16 + lquad * 4 + r;
                const float c1 = bf2f(sCT[(2 * m) * 136 + j]);
                const float c2 = bf2f(sCT[(2 * m + 1) * 136 + j]);
                const float iv = sigm(acc[0][i][jj][r] + bi);
                const float uv = tanhf(acc[1][i][jj][r] + bu);
                const float ov = sigm(acc[2][i][jj][r] + bo);
                const float f1 = sigm(acc[3][i][jj][r] + b1);
                const float f2 = sigm(acc[4][i][jj][r] + b2);
                const float c = iv * uv + f1 * c1 + f2 * c2;
                cv[i][jj][r] = c;
                hv[i][jj][r] = ov * tanhf(c);
            }
        }
    __syncthreads();   // all child reads complete before overwriting sCT

    // ---- write c (rows 0..31) and h (rows 32..63) tiles ----
#pragma unroll
    for (int i = 0; i < 2; ++i)
#pragma unroll
        for (int jj = 0; jj < 2; ++jj) {
            const int j = w * 32 + jj * 16 + lrow;
#pragma unroll
            for (int r = 0; r < 4; ++r) {
                const int m = i * 16 + lquad * 4 + r;
                sCT[m * 136 + j] = f2bf(cv[i][jj][r]);
                sCT[(32 + m) * 136 + j] = f2bf(hv[i][jj][r]);
            }
        }
    __syncthreads();

    // ---- coalesced flush: rows 0..31 -> c_all, rows 32..63 -> h_all ----
#pragma unroll
    for (int q = 0; q < 4; ++q) {
        int ci = t + 256 * q;               // 0..1023
        int row = ci >> 4;                  // 0..63
        int c8 = (ci & 15) * 8;
        int m = row & 31;
        if (m0 + m < nm) {
            bf16raw* dst = (row < 32) ? c_all : h_all;
            *(short8*)(dst + ((long)off + m0 + m) * 128 + c8) = *(const short8*)&sCT[row * 136 + c8];
        }
    }

    // ---- logits + loss: 8 threads per node ----
    {
        const int row = t >> 3, oct = t & 7;
        float p[5] = {0.f, 0.f, 0.f, 0.f, 0.f};
#pragma unroll
        for (int k0 = 0; k0 < 16; ++k0) {
            const int k = oct * 16 + k0;
            float hval = bf2f(sCT[(32 + row) * 136 + k]);
#pragma unroll
            for (int l = 0; l < 5; l++) p[l] += hval * sWout[l * 128 + k];
        }
#pragma unroll
        for (int l = 0; l < 5; l++) {
            p[l] += __shfl_down(p[l], 4);
            p[l] += __shfl_down(p[l], 2);
            p[l] += __shfl_down(p[l], 1);
        }
        if (oct == 0 && m0 + row < nm) {
            const long g = (long)off + m0 + row;
            float lg[5], mx = -1e30f;
#pragma unroll
            for (int l = 0; l < 5; l++) {
                lg[l] = p[l] + bout[l];
                mx = fmaxf(mx, lg[l]);
            }
            float se = 0.f;
#pragma unroll
            for (int l = 0; l < 5; l++) se += __expf(lg[l] - mx);
            float lse = __logf(se) + mx;
            float lossNode = lse - lg[labels[g]];
            if (leafkids) {
                const float* lv1 = lossv6 + (long)words[2 * g + 1] * 6;
                const float* lv2 = lossv6 + (long)words[2 * g + 2] * 6;
                lossNode += (lv1[5] - lv1[labels[2 * g + 1]])
                          + (lv2[5] - lv2[labels[2 * g + 2]]);
            }
            atomicAdd(&partials[(int)(g & 1023)], lossNode);
            if (isroot) {
#pragma unroll
                for (int l = 0; l < 5; l++) out[l] = lg[l] - lse;
            }
        }
    }
}

__global__ __launch_bounds__(256) void k3_reduce(const float* __restrict__ partials,
                                                 float* __restrict__ out)
{
    const int t = threadIdx.x;
    float s = 0.f;
    for (int i = t; i < 1024; i += 256) s += partials[i];
#pragma unroll
    for (int d = 32; d > 0; d >>= 1) s += __shfl_down(s, d);
    __shared__ float red[4];
    if ((t & 63) == 0) red[t >> 6] = s;
    __syncthreads();
    if (t == 0) out[5] = red[0] + red[1] + red[2] + red[3];
}

// ---------------------------------------------------------------------------
extern "C" void kernel_launch(void* const* d_in, const int* in_sizes, int n_in,
                              void* d_out, int out_size, void* d_ws, size_t ws_size,
                              hipStream_t stream)
{
    const float* embeds = (const float*)d_in[0];
    const int* words = (const int*)d_in[1];
    const int* labels = (const int*)d_in[2];
    const float* Wix = (const float*)d_in[5],  *bix  = (const float*)d_in[6];
    const float* Wih = (const float*)d_in[7],  *bih  = (const float*)d_in[8];
    const float* Wfx = (const float*)d_in[9],  *bfx  = (const float*)d_in[10];
    const float* Wfh = (const float*)d_in[11], *bfh  = (const float*)d_in[12];
    const float* Wox = (const float*)d_in[13], *box_ = (const float*)d_in[14];
    const float* Woh = (const float*)d_in[15], *boh  = (const float*)d_in[16];
    const float* Wux = (const float*)d_in[17], *bux  = (const float*)d_in[18];
    const float* Wuh = (const float*)d_in[19], *buh  = (const float*)d_in[20];
    const float* Wout = (const float*)d_in[21], *bout = (const float*)d_in[22];
    float* out = (float*)d_out;

    char* ws = (char*)d_ws;
    const size_t treeElems = (size_t)NINT * 128;
    bf16raw* h_all = (bf16raw*)ws;
    bf16raw* c_all = h_all + treeElems;
    bf16raw* embeds_bf = c_all + treeElems;
    bf16raw* Bfrag = embeds_bf + (size_t)NVOCAB * 128;
    bf16raw* hc_leaf = Bfrag + 640 * 384;
    float* lossv6 = (float*)(hc_leaf + (size_t)NVOCAB * 256);
    float* bias_cat = lossv6 + (size_t)NVOCAB * 6;
    float* partials = bias_cat + 640;

    k_prep_embeds<<<(NVOCAB * 128 / 4 + 255) / 256, 256, 0, stream>>>(
        embeds, embeds_bf, NVOCAB * 128 / 4);
    k_prep_bcat<<<640, 128, 0, stream>>>(Wix, bix, Wih, bih, Wfx, bfx, Wfh, bfh,
                                         Wox, box_, Woh, boh, Wux, bux, Wuh, buh,
                                         Bfrag, bias_cat);
    hipMemsetAsync(partials, 0, 1024 * sizeof(float), stream);

    k_leafpre<<<(NVOCAB + 127) / 128, 256, 0, stream>>>(
        embeds_bf, Bfrag, bias_cat, Wout, bout, hc_leaf, lossv6, 0, NVOCAB);

    for (int l = DEPTH - 2; l >= 0; --l) {
        const int n = 1 << l;
        const int off = n - 1;
        k_level32<<<dim3((n + 31) / 32), 256, 0, stream>>>(
            embeds_bf, words, labels, h_all, c_all, hc_leaf, lossv6,
            Bfrag, bias_cat, Wout, bout, partials, out,
            off, n, (l == DEPTH - 2) ? 1 : 0, (l == 0) ? 1 : 0);
    }
    k3_reduce<<<1, 256, 0, stream>>>(partials, out);
}